// Round 1
// baseline (432.793 us; speedup 1.0000x reference)
//
#include <hip/hip_runtime.h>

#define EPS 1e-4f
#define FRAMES 4000

// One wave (64 lanes) per row. Each chunk: 64 lanes x float4 = 256 elements.
// Per-lane serial scan of 4 elems, then wave-inclusive scan of lane totals
// (sum and sumsq scanned together), carry running prefix across chunks.
__global__ __launch_bounds__(256) void cumnorm_kernel(const float* __restrict__ x,
                                                      float* __restrict__ out,
                                                      int rows) {
    const int wavesPerBlock = blockDim.x >> 6;
    const int row  = blockIdx.x * wavesPerBlock + (threadIdx.x >> 6);
    const int lane = threadIdx.x & 63;
    if (row >= rows) return;

    const float4* __restrict__ xr = (const float4*)(x + (size_t)row * FRAMES);
    float4* __restrict__ outr     = (float4*)(out + (size_t)row * FRAMES);

    const int nvec = FRAMES >> 2;  // 1000 float4 per row
    float carry_s = 0.0f, carry_q = 0.0f;

    for (int base = 0; base < nvec; base += 64) {
        const int idx = base + lane;
        float4 v = make_float4(0.0f, 0.0f, 0.0f, 0.0f);
        if (idx < nvec) v = xr[idx];

        // per-lane serial inclusive scans of the 4 elements
        float s0 = v.x;
        float s1 = s0 + v.y;
        float s2 = s1 + v.z;
        float s3 = s2 + v.w;
        float q0 = v.x * v.x;
        float q1 = fmaf(v.y, v.y, q0);
        float q2 = fmaf(v.z, v.z, q1);
        float q3 = fmaf(v.w, v.w, q2);

        // wave-inclusive scan of lane totals (s3, q3) over 64 lanes
        float ss = s3, qq = q3;
        #pragma unroll
        for (int d = 1; d < 64; d <<= 1) {
            float us = __shfl_up(ss, d, 64);
            float uq = __shfl_up(qq, d, 64);
            if (lane >= d) { ss += us; qq += uq; }
        }

        // chunk totals (lane 63 holds full-chunk inclusive sum; inactive lanes added 0)
        const float tot_s = __shfl(ss, 63, 64);
        const float tot_q = __shfl(qq, 63, 64);

        // exclusive prefix for this lane within the row
        const float excl_s = (ss - s3) + carry_s;
        const float excl_q = (qq - q3) + carry_q;

        if (idx < nvec) {
            const float base_cnt = (float)(idx << 2);
            float4 r;
            {
                const float cs = excl_s + s0, cq = excl_q + q0;
                const float inv  = __builtin_amdgcn_rcpf(base_cnt + 1.0f);
                const float mean = cs * inv;
                const float var  = fmaf(-mean, mean, cq * inv);
                r.x = (v.x - mean) * __builtin_amdgcn_rsqf(var + EPS);
            }
            {
                const float cs = excl_s + s1, cq = excl_q + q1;
                const float inv  = __builtin_amdgcn_rcpf(base_cnt + 2.0f);
                const float mean = cs * inv;
                const float var  = fmaf(-mean, mean, cq * inv);
                r.y = (v.y - mean) * __builtin_amdgcn_rsqf(var + EPS);
            }
            {
                const float cs = excl_s + s2, cq = excl_q + q2;
                const float inv  = __builtin_amdgcn_rcpf(base_cnt + 3.0f);
                const float mean = cs * inv;
                const float var  = fmaf(-mean, mean, cq * inv);
                r.z = (v.z - mean) * __builtin_amdgcn_rsqf(var + EPS);
            }
            {
                const float cs = excl_s + s3, cq = excl_q + q3;
                const float inv  = __builtin_amdgcn_rcpf(base_cnt + 4.0f);
                const float mean = cs * inv;
                const float var  = fmaf(-mean, mean, cq * inv);
                r.w = (v.w - mean) * __builtin_amdgcn_rsqf(var + EPS);
            }
            outr[idx] = r;
        }

        carry_s += tot_s;
        carry_q += tot_q;
    }
}

extern "C" void kernel_launch(void* const* d_in, const int* in_sizes, int n_in,
                              void* d_out, int out_size, void* d_ws, size_t ws_size,
                              hipStream_t stream) {
    const float* x = (const float*)d_in[0];
    float* out = (float*)d_out;
    const int rows = in_sizes[0] / FRAMES;  // 32*512 = 16384

    const int block = 256;                  // 4 waves per block, 1 wave per row
    const int rowsPerBlock = block / 64;
    const int grid = (rows + rowsPerBlock - 1) / rowsPerBlock;
    cumnorm_kernel<<<grid, block, 0, stream>>>(x, out, rows);
}